// Round 2
// baseline (701.201 us; speedup 1.0000x reference)
//
#include <hip/hip_runtime.h>
#include <math.h>

// GDecode: logits[m,v] = sum_{h,k} phi[m, h*64+k] * psi[perm[h,v], k]; out = softmax_v(logits)
// M=2048, C=512 (G=8 x K=64), V=32000.
// Fast path: pre-convert psi->f16 and phi->Dekker(hi,lo) f16 into ws, then an LDS-free
// MFMA kernel loads A frags coalesced and gathers B frags per-lane (psi16 is L2-resident).

#define M_ROWS 2048
#define V_DIM  32000
#define C_DIM  512
#define G_DIM  8
#define K_DIM  64
#define BM     128
#define BV     128
#define BK     32
#define NVBLK  (V_DIM / BV)   // 250
#define LDS_ROW 40            // fallback kernel only

typedef _Float16 f16x8 __attribute__((ext_vector_type(8)));
typedef _Float16 f16x4 __attribute__((ext_vector_type(4)));
typedef float    f32x4 __attribute__((ext_vector_type(4)));

// ---------------- pre-convert kernels ----------------

__global__ __launch_bounds__(256) void conv_psi(const float* __restrict__ psi,
                                                _Float16* __restrict__ psi16)
{
  int i = blockIdx.x * 256 + threadIdx.x;   // float4 index; total 512000
  float4 x = ((const float4*)psi)[i];
  f16x4 w = {(_Float16)x.x, (_Float16)x.y, (_Float16)x.z, (_Float16)x.w};
  *(f16x4*)(psi16 + (size_t)i * 4) = w;
}

__global__ __launch_bounds__(256) void conv_phi(const float* __restrict__ phi,
                                                _Float16* __restrict__ phiH,
                                                _Float16* __restrict__ phiL)
{
  int i = blockIdx.x * 256 + threadIdx.x;   // float4 index; total 262144
  float4 x = ((const float4*)phi)[i];
  _Float16 h0 = (_Float16)x.x, h1 = (_Float16)x.y, h2 = (_Float16)x.z, h3 = (_Float16)x.w;
  f16x4 hi = {h0, h1, h2, h3};
  f16x4 lo = {(_Float16)(x.x - (float)h0), (_Float16)(x.y - (float)h1),
              (_Float16)(x.z - (float)h2), (_Float16)(x.w - (float)h3)};
  *(f16x4*)(phiH + (size_t)i * 4) = hi;
  *(f16x4*)(phiL + (size_t)i * 4) = lo;
}

// ---------------- LDS-free MFMA GEMM ----------------

__global__ __launch_bounds__(256, 3) void gdecode_gemm_direct(
    const _Float16* __restrict__ phiH, const _Float16* __restrict__ phiL,
    const _Float16* __restrict__ psi16, const int* __restrict__ perm, const int pstride,
    float* __restrict__ out, float* __restrict__ smax, float* __restrict__ ssum)
{
  __shared__ float red[4 * BM];           // [BM][2] max | [BM][2] sum
  float* redmax = red;
  float* redsum = red + 2 * BM;

  const int t     = threadIdx.x;
  const int vbase = blockIdx.x * BV;
  const int mbase = blockIdx.y * BM;
  const int wid   = t >> 6;
  const int lane  = t & 63;
  const int wm    = wid & 1;
  const int wv    = wid >> 1;
  const int lrow  = lane & 15;
  const int quad  = lane >> 4;

  f32x4 acc[4][4] = {};

  const int arow0 = mbase + wm * 64 + lrow;
  const _Float16* pH = phiH + (size_t)arow0 * C_DIM + quad * 8;
  const _Float16* pL = phiL + (size_t)arow0 * C_DIM + quad * 8;
  const int vcol0 = vbase + wv * 64 + lrow;

  #pragma unroll
  for (int h = 0; h < 8; ++h) {
    int pr[4];
    #pragma unroll
    for (int j = 0; j < 4; ++j)
      pr[j] = perm[(size_t)(h * V_DIM + vcol0 + j * 16) * pstride];

    #pragma unroll
    for (int half = 0; half < 2; ++half) {
      const int cb = h * 64 + half * 32;
      f16x8 ah[4], al[4], bf[4];
      #pragma unroll
      for (int i = 0; i < 4; ++i) {
        ah[i] = *(const f16x8*)(pH + (size_t)i * 16 * C_DIM + cb);
        al[i] = *(const f16x8*)(pL + (size_t)i * 16 * C_DIM + cb);
      }
      #pragma unroll
      for (int j = 0; j < 4; ++j)
        bf[j] = *(const f16x8*)(psi16 + (size_t)pr[j] * K_DIM + half * 32 + quad * 8);

      #pragma unroll
      for (int i = 0; i < 4; ++i) {
        #pragma unroll
        for (int j = 0; j < 4; ++j) {
          acc[i][j] = __builtin_amdgcn_mfma_f32_16x16x32_f16(ah[i], bf[j], acc[i][j], 0, 0, 0);
          acc[i][j] = __builtin_amdgcn_mfma_f32_16x16x32_f16(al[i], bf[j], acc[i][j], 0, 0, 0);
        }
      }
    }
  }

  // ---- epilogue: per-(row, vtile) stats + raw logit store ----
  const int rowb = wm * 64;
  #pragma unroll
  for (int i = 0; i < 4; ++i) {
    #pragma unroll
    for (int r = 0; r < 4; ++r) {
      float v = fmaxf(fmaxf(acc[i][0][r], acc[i][1][r]),
                      fmaxf(acc[i][2][r], acc[i][3][r]));
      v = fmaxf(v, __shfl_xor(v, 1));
      v = fmaxf(v, __shfl_xor(v, 2));
      v = fmaxf(v, __shfl_xor(v, 4));
      v = fmaxf(v, __shfl_xor(v, 8));
      if (lrow == 0) redmax[(rowb + i * 16 + quad * 4 + r) * 2 + wv] = v;
    }
  }
  __syncthreads();
  float gmx[4][4];
  #pragma unroll
  for (int i = 0; i < 4; ++i) {
    #pragma unroll
    for (int r = 0; r < 4; ++r) {
      int row = rowb + i * 16 + quad * 4 + r;
      gmx[i][r] = fmaxf(redmax[row * 2], redmax[row * 2 + 1]);
    }
  }
  #pragma unroll
  for (int i = 0; i < 4; ++i) {
    #pragma unroll
    for (int r = 0; r < 4; ++r) {
      float s = __expf(acc[i][0][r] - gmx[i][r]) + __expf(acc[i][1][r] - gmx[i][r])
              + __expf(acc[i][2][r] - gmx[i][r]) + __expf(acc[i][3][r] - gmx[i][r]);
      s += __shfl_xor(s, 1);
      s += __shfl_xor(s, 2);
      s += __shfl_xor(s, 4);
      s += __shfl_xor(s, 8);
      if (lrow == 0) redsum[(rowb + i * 16 + quad * 4 + r) * 2 + wv] = s;
    }
  }
  __syncthreads();
  if (t < BM) {
    int row = t;
    size_t o = (size_t)(mbase + row) * NVBLK + blockIdx.x;
    smax[o] = fmaxf(redmax[row * 2], redmax[row * 2 + 1]);
    ssum[o] = redsum[row * 2] + redsum[row * 2 + 1];
  }
  #pragma unroll
  for (int i = 0; i < 4; ++i) {
    #pragma unroll
    for (int j = 0; j < 4; ++j) {
      #pragma unroll
      for (int r = 0; r < 4; ++r) {
        int grow = mbase + rowb + i * 16 + quad * 4 + r;
        int gcol = vbase + wv * 64 + j * 16 + lrow;
        out[(size_t)grow * V_DIM + gcol] = acc[i][j][r];
      }
    }
  }
}

// ---------------- softmax finalize (fast path) ----------------

__global__ __launch_bounds__(256) void gdecode_stats(
    const float* __restrict__ smax, const float* __restrict__ ssum,
    float* __restrict__ rowM, float* __restrict__ rowInv)
{
  __shared__ float sbuf[4];
  __shared__ float sM;
  const int m = blockIdx.x;
  const int t = threadIdx.x;
  const float* rm = smax + (size_t)m * NVBLK;
  const float* rs = ssum + (size_t)m * NVBLK;

  float lm = -3.4e38f;
  for (int i = t; i < NVBLK; i += 256) lm = fmaxf(lm, rm[i]);
  for (int d = 1; d < 64; d <<= 1) lm = fmaxf(lm, __shfl_xor(lm, d));
  if ((t & 63) == 0) sbuf[t >> 6] = lm;
  __syncthreads();
  if (t == 0) sM = fmaxf(fmaxf(sbuf[0], sbuf[1]), fmaxf(sbuf[2], sbuf[3]));
  __syncthreads();
  const float M = sM;

  float ls = 0.f;
  for (int i = t; i < NVBLK; i += 256) ls += rs[i] * __expf(rm[i] - M);
  for (int d = 1; d < 64; d <<= 1) ls += __shfl_xor(ls, d);
  if ((t & 63) == 0) sbuf[t >> 6] = ls;
  __syncthreads();
  if (t == 0) {
    rowM[m]   = M;
    rowInv[m] = 1.f / (sbuf[0] + sbuf[1] + sbuf[2] + sbuf[3]);
  }
}

__global__ __launch_bounds__(256) void gdecode_scale(
    float* __restrict__ out, const float* __restrict__ rowM, const float* __restrict__ rowInv)
{
  const int m  = blockIdx.y;
  const int c4 = blockIdx.x * 256 + threadIdx.x;       // float4 index in row; 8000/row
  if (c4 >= V_DIM / 4) return;
  const float M   = rowM[m];
  const float inv = rowInv[m];
  float4* row = (float4*)(out + (size_t)m * V_DIM);
  float4 x = row[c4];
  x.x = __expf(x.x - M) * inv;
  x.y = __expf(x.y - M) * inv;
  x.z = __expf(x.z - M) * inv;
  x.w = __expf(x.w - M) * inv;
  row[c4] = x;
}

// ---------------- fallback path (round-1 kernels, no/small ws) ----------------

__global__ __launch_bounds__(256, 2) void gdecode_gemm_lds(
    const float* __restrict__ phi, const float* __restrict__ psi,
    const int* __restrict__ perm, const int pstride, float* __restrict__ out)
{
  __shared__ __align__(16) _Float16 lds[3 * BM * LDS_ROW];
  _Float16* sAhi = lds;
  _Float16* sAlo = lds + BM * LDS_ROW;
  _Float16* sB   = lds + 2 * BM * LDS_ROW;

  const int t     = threadIdx.x;
  const int vbase = blockIdx.x * BV;
  const int mbase = blockIdx.y * BM;
  const int kg = t & 7;
  const int r0 = t >> 3;
  const int wid  = t >> 6;
  const int lane = t & 63;
  const int wm   = wid & 1;
  const int wv   = wid >> 1;
  const int lrow = lane & 15;
  const int quad = lane >> 4;

  f32x4 acc[4][4] = {};

  for (int it = 0; it < 16; ++it) {
    const int cb  = it * BK;
    const int h   = cb >> 6;
    const int kin = cb & 63;

    float4 av[4], bv[4];
    #pragma unroll
    for (int i = 0; i < 4; ++i)
      av[i] = *(const float4*)(phi + (size_t)(mbase + r0 + i * 32) * C_DIM + cb + kg * 4);
    #pragma unroll
    for (int i = 0; i < 4; ++i) {
      int pr = perm[(size_t)(h * V_DIM + vbase + r0 + i * 32) * pstride];
      bv[i]  = *(const float4*)(psi + (size_t)pr * K_DIM + kin + kg * 4);
    }

    __syncthreads();
    #pragma unroll
    for (int i = 0; i < 4; ++i) {
      int m = r0 + i * 32;
      float4 x = av[i];
      _Float16 h0 = (_Float16)x.x, h1 = (_Float16)x.y,
               h2 = (_Float16)x.z, h3 = (_Float16)x.w;
      f16x4 hi = {h0, h1, h2, h3};
      f16x4 lo = {(_Float16)(x.x - (float)h0), (_Float16)(x.y - (float)h1),
                  (_Float16)(x.z - (float)h2), (_Float16)(x.w - (float)h3)};
      *(f16x4*)(sAhi + m * LDS_ROW + kg * 4) = hi;
      *(f16x4*)(sAlo + m * LDS_ROW + kg * 4) = lo;
    }
    #pragma unroll
    for (int i = 0; i < 4; ++i) {
      float4 x = bv[i];
      f16x4 w = {(_Float16)x.x, (_Float16)x.y, (_Float16)x.z, (_Float16)x.w};
      *(f16x4*)(sB + (r0 + i * 32) * LDS_ROW + kg * 4) = w;
    }
    __syncthreads();

    f16x8 ah[4], al[4], bf[4];
    #pragma unroll
    for (int i = 0; i < 4; ++i) {
      ah[i] = *(const f16x8*)(sAhi + (wm * 64 + i * 16 + lrow) * LDS_ROW + quad * 8);
      al[i] = *(const f16x8*)(sAlo + (wm * 64 + i * 16 + lrow) * LDS_ROW + quad * 8);
      bf[i] = *(const f16x8*)(sB   + (wv * 64 + i * 16 + lrow) * LDS_ROW + quad * 8);
    }
    #pragma unroll
    for (int i = 0; i < 4; ++i) {
      #pragma unroll
      for (int j = 0; j < 4; ++j) {
        acc[i][j] = __builtin_amdgcn_mfma_f32_16x16x32_f16(ah[i], bf[j], acc[i][j], 0, 0, 0);
        acc[i][j] = __builtin_amdgcn_mfma_f32_16x16x32_f16(al[i], bf[j], acc[i][j], 0, 0, 0);
      }
    }
  }

  #pragma unroll
  for (int i = 0; i < 4; ++i) {
    #pragma unroll
    for (int j = 0; j < 4; ++j) {
      #pragma unroll
      for (int r = 0; r < 4; ++r) {
        int grow = mbase + wm * 64 + i * 16 + quad * 4 + r;
        int gcol = vbase + wv * 64 + j * 16 + lrow;
        out[(size_t)grow * V_DIM + gcol] = acc[i][j][r];
      }
    }
  }
}

__global__ __launch_bounds__(256) void gdecode_softmax_nows(float* __restrict__ out)
{
  __shared__ float sbuf[4];
  __shared__ float sM, sInv;
  const int m = blockIdx.x;
  const int t = threadIdx.x;
  float4* row = (float4*)(out + (size_t)m * V_DIM);

  float lm = -3.4e38f;
  for (int i = t; i < V_DIM / 4; i += 256) {
    float4 x = row[i];
    lm = fmaxf(lm, fmaxf(fmaxf(x.x, x.y), fmaxf(x.z, x.w)));
  }
  for (int d = 1; d < 64; d <<= 1) lm = fmaxf(lm, __shfl_xor(lm, d));
  if ((t & 63) == 0) sbuf[t >> 6] = lm;
  __syncthreads();
  if (t == 0) sM = fmaxf(fmaxf(sbuf[0], sbuf[1]), fmaxf(sbuf[2], sbuf[3]));
  __syncthreads();
  const float M = sM;

  float ls = 0.f;
  for (int i = t; i < V_DIM / 4; i += 256) {
    float4 x = row[i];
    ls += __expf(x.x - M) + __expf(x.y - M) + __expf(x.z - M) + __expf(x.w - M);
  }
  for (int d = 1; d < 64; d <<= 1) ls += __shfl_xor(ls, d);
  if ((t & 63) == 0) sbuf[t >> 6] = ls;
  __syncthreads();
  if (t == 0) sInv = 1.f / (sbuf[0] + sbuf[1] + sbuf[2] + sbuf[3]);
  __syncthreads();
  const float inv = sInv;

  for (int i = t; i < V_DIM / 4; i += 256) {
    float4 x = row[i];
    x.x = __expf(x.x - M) * inv;
    x.y = __expf(x.y - M) * inv;
    x.z = __expf(x.z - M) * inv;
    x.w = __expf(x.w - M) * inv;
    row[i] = x;
  }
}

// ---------------- launch ----------------

extern "C" void kernel_launch(void* const* d_in, const int* in_sizes, int n_in,
                              void* d_out, int out_size, void* d_ws, size_t ws_size,
                              hipStream_t stream)
{
  const float* phi  = (const float*)d_in[0];   // [2048][512] fp32
  const float* psi  = (const float*)d_in[1];   // [32000][64] fp32
  const int*   perm = (const int*)d_in[2];     // [8][32000]; int64 words -> stride 2
  const int pstride = (in_sizes[2] == 2 * G_DIM * V_DIM) ? 2 : 1;
  float* out = (float*)d_out;

  // ws layout (bytes):
  const size_t off_psi16 = 0;                                  // 4,096,000
  const size_t off_phiH  = off_psi16 + (size_t)V_DIM * K_DIM * 2;
  const size_t off_phiL  = off_phiH + (size_t)M_ROWS * C_DIM * 2;
  const size_t off_smax  = off_phiL + (size_t)M_ROWS * C_DIM * 2;
  const size_t off_ssum  = off_smax + (size_t)M_ROWS * NVBLK * 4;
  const size_t off_rowM  = off_ssum + (size_t)M_ROWS * NVBLK * 4;
  const size_t off_rowI  = off_rowM + (size_t)M_ROWS * 4;
  const size_t need      = off_rowI + (size_t)M_ROWS * 4;

  if (d_ws != nullptr && ws_size >= need) {
    char* ws = (char*)d_ws;
    _Float16* psi16 = (_Float16*)(ws + off_psi16);
    _Float16* phiH  = (_Float16*)(ws + off_phiH);
    _Float16* phiL  = (_Float16*)(ws + off_phiL);
    float* smax   = (float*)(ws + off_smax);
    float* ssum   = (float*)(ws + off_ssum);
    float* rowM   = (float*)(ws + off_rowM);
    float* rowInv = (float*)(ws + off_rowI);

    conv_psi<<<(V_DIM * K_DIM / 4) / 256, 256, 0, stream>>>(psi, psi16);
    conv_phi<<<(M_ROWS * C_DIM / 4) / 256, 256, 0, stream>>>(phi, phiH, phiL);

    dim3 grid(NVBLK, M_ROWS / BM);   // 250 x 16
    gdecode_gemm_direct<<<grid, 256, 0, stream>>>(phiH, phiL, psi16, perm, pstride,
                                                  out, smax, ssum);
    gdecode_stats<<<M_ROWS, 256, 0, stream>>>(smax, ssum, rowM, rowInv);
    dim3 sgrid((V_DIM / 4 + 255) / 256, M_ROWS);   // 32 x 2048
    gdecode_scale<<<sgrid, 256, 0, stream>>>(out, rowM, rowInv);
  } else {
    dim3 grid(NVBLK, M_ROWS / BM);
    gdecode_gemm_lds<<<grid, 256, 0, stream>>>(phi, psi, perm, pstride, out);
    gdecode_softmax_nows<<<M_ROWS, 256, 0, stream>>>(out);
  }
}